// Round 4
// baseline (11783.096 us; speedup 1.0000x reference)
//
#include <hip/hip_runtime.h>
#include <math.h>

#define T_STEPS 1000
#define KK 32
#define D0 128
#define D1 256
#define D2 512
#define IMGH 105
#define IMGW 105
#define NPIX (IMGH*IMGW)
#define DTTAU 0.01f

#define NB 256
#define NT 512

// ---- workspace float offsets ----
#define OFF_M0   0            // 128*128
#define OFF_X0S  16384        // 2*128  ping-pong x0
#define OFF_X1S  16640        // 2*256
#define OFF_X2S  17152        // 2*512
#define OFF_S2T  18176        // 1000*512  (x2 AFTER step t)
#define OFF_PA   530176       // 1000*3
#define OFF_PXYP 533176       // 1000*3
#define OFF_PENS 536176       // 2
#define OFF_CTR  536178       // 1 int

// ---- output float offsets (reference return order, each stacked over T) ----
#define OA0  0
#define OA1  32000
#define OA2  64000
#define OU0  96000
#define OU1  224000
#define OU2  480000
#define OX0  992000
#define OX1  1120000
#define OX2  1376000
#define OPEN 1888000
#define OPXY 1890000
#define OPDLP 12915000

#define DOT4(a,b) ((a).x*(b).x + (a).y*(b).y + (a).z*(b).z + (a).w*(b).w)

__device__ __forceinline__ float waveReduceSum(float v) {
    for (int m = 32; m >= 1; m >>= 1) v += __shfl_xor(v, m, 64);
    return v;
}

// ---------------- setup: init exchange slots, pen0, barrier counter ----------------
__global__ __launch_bounds__(256) void setup_kernel(
    const void* __restrict__ dataRaw, const float* __restrict__ z2,
    float* __restrict__ ws)
{
    if (blockIdx.x != 0) return;
    int tid = threadIdx.x;

    if (tid < D0) (ws + OFF_X0S)[tid] = z2[tid];           // parity-0 slots = x(0)
    if (tid < D1) (ws + OFF_X1S)[tid] = 0.f;
    for (int i = tid; i < D2; i += 256) (ws + OFF_X2S)[i] = 0.f;
    if (tid == 0) *(int*)(ws + OFF_CTR) = 0;

    // pen0 = argwhere(data)[0]; robust to bool stored as uint8 or int32
    __shared__ int sMin;
    if (tid == 0) sMin = 0x7fffffff;
    __syncthreads();
    const unsigned char* db = (const unsigned char*)dataRaw;
    for (int i = tid; i < NPIX; i += 256) if (db[i]) atomicMin(&sMin, i);
    __syncthreads();
    if (sMin == 0x7fffffff) {
        const int* di = (const int*)dataRaw;
        for (int i = tid; i < NPIX; i += 256) if (di[i] != 0) atomicMin(&sMin, i);
    }
    __syncthreads();
    if (tid == 0) {
        int idx = (sMin == 0x7fffffff) ? 0 : sMin;
        (ws + OFF_PENS)[0] = (float)(idx / IMGW);
        (ws + OFF_PENS)[1] = (float)(idx % IMGW);
    }
}

// ---------------- M0 = sum_k z1[k] * A0[k] ----------------
__global__ __launch_bounds__(256) void m0_kernel(
    const float* __restrict__ z1, const float* __restrict__ A0, float* __restrict__ ws)
{
    int idx = blockIdx.x * 256 + threadIdx.x;
    if (idx < D0 * D0) {
        float s = 0.f;
        for (int k = 0; k < KK; k++) s += z1[k] * A0[(size_t)k * D0 * D0 + idx];
        ws[OFF_M0 + idx] = s;
    }
}

// ---------------- trivial outputs: alpha0 broadcast, u0 zeros ----------------
__global__ __launch_bounds__(256) void fill_kernel(const float* __restrict__ z1, float* __restrict__ out)
{
    size_t gid = (size_t)blockIdx.x * blockDim.x + threadIdx.x;
    size_t nthr = (size_t)gridDim.x * blockDim.x;
    for (size_t i = gid; i < 32000; i += nthr) out[OA0 + i] = z1[i & 31];
    for (size_t i = gid; i < 128000; i += nthr) out[OU0 + i] = 0.f;
}

// ---------------- persistent recurrence: A in registers, 1000 steps, ws barrier ----------------
// block b owns: L2 elems {2b,2b+1} (all 32 k), L1 elem {b}, L0 row {b} (b<128).
// thread roles: k = tid>>4 (0..31), c = tid&15 (slice of the row).
__global__ __launch_bounds__(NT, 2) void persist_kernel(
    const float* __restrict__ A1, const float* __restrict__ A2,
    const float* __restrict__ Wu0, const float* __restrict__ Wu1,
    const float* __restrict__ Wa0, const float* __restrict__ Wa1,
    const float* __restrict__ ba0, const float* __restrict__ ba1,
    const float* __restrict__ gam,
    float* __restrict__ ws, float* __restrict__ out)
{
    const int b = blockIdx.x;
    const int tid = threadIdx.x;
    const int lane = tid & 63;
    const int w = tid >> 6;
    const int k = tid >> 4;
    const int c = tid & 15;

    // ---- load A into registers (once; statically indexed) ----
    float4 a2r0[8], a2r1[8], a1r[4];
    {
        const float4* p0 = (const float4*)(A2 + ((size_t)k * D2 + 2 * b) * D2 + c * 32);
        const float4* p1 = (const float4*)(A2 + ((size_t)k * D2 + 2 * b + 1) * D2 + c * 32);
        #pragma unroll
        for (int jj = 0; jj < 8; ++jj) { a2r0[jj] = p0[jj]; a2r1[jj] = p1[jj]; }
        const float4* p2 = (const float4*)(A1 + ((size_t)k * D1 + b) * D1 + c * 16);
        #pragma unroll
        for (int jj = 0; jj < 4; ++jj) a1r[jj] = p2[jj];
    }
    const float g0 = gam[0], g1 = gam[1], g2 = gam[2];

    __shared__ __align__(16) float x0s[D0];
    __shared__ __align__(16) float x1s[16 * 20];   // chunk c: 16 floats at c*20 (pad vs bank conflicts)
    __shared__ __align__(16) float x2s[16 * 36];   // chunk c: 32 floats at c*36
    __shared__ float pre[64];
    __shared__ float al2[KK], al1[KK];
    __shared__ float red2a[KK], red2b[KK], red1[KK];
    __shared__ float uS[3];

    float* X0S = ws + OFF_X0S;
    float* X1S = ws + OFF_X1S;
    float* X2S = ws + OFF_X2S;
    int* ctr = (int*)(ws + OFF_CTR);

    #pragma unroll 1
    for (int t = 0; t < T_STEPS; ++t) {
        const int p = t & 1;

        // ---- P1: fetch x(t) (agent-scope: bypass non-coherent L2) ----
        if (tid < D0)
            x0s[tid] = __hip_atomic_load(&X0S[p * D0 + tid], __ATOMIC_RELAXED, __HIP_MEMORY_SCOPE_AGENT);
        if (tid < D1)
            x1s[(tid >> 4) * 20 + (tid & 15)] =
                __hip_atomic_load(&X1S[p * D1 + tid], __ATOMIC_RELAXED, __HIP_MEMORY_SCOPE_AGENT);
        x2s[(tid >> 5) * 36 + (tid & 31)] =
            __hip_atomic_load(&X2S[p * D2 + tid], __ATOMIC_RELAXED, __HIP_MEMORY_SCOPE_AGENT);
        __syncthreads();

        // ---- P2: alpha pre-activations (all threads; row k, slice c) ----
        {
            float s = 0.f;
            const float4* wr = (const float4*)(Wa1 + (size_t)k * D1 + c * 16);
            const float4* xc = (const float4*)(x1s + c * 20);
            #pragma unroll
            for (int jj = 0; jj < 4; ++jj) { float4 a = wr[jj], x = xc[jj]; s += DOT4(a, x); }
            s += __shfl_xor(s, 1, 64); s += __shfl_xor(s, 2, 64);
            s += __shfl_xor(s, 4, 64); s += __shfl_xor(s, 8, 64);
            if (c == 0) pre[k] = s + ba1[k];

            float s1 = 0.f;
            const float4* wr1 = (const float4*)(Wa0 + (size_t)k * D0 + c * 8);
            const float4* xc1 = (const float4*)(x0s + c * 8);
            #pragma unroll
            for (int jj = 0; jj < 2; ++jj) { float4 a = wr1[jj], x = xc1[jj]; s1 += DOT4(a, x); }
            s1 += __shfl_xor(s1, 1, 64); s1 += __shfl_xor(s1, 2, 64);
            s1 += __shfl_xor(s1, 4, 64); s1 += __shfl_xor(s1, 8, 64);
            if (c == 0) pre[32 + k] = s1 + ba0[k];
        }
        __syncthreads();

        // ---- P3: softmaxes (wave0) || u2 (waves4,5) || u1 (wave6) || M0+x0n (wave7) ----
        if (w == 0) {
            float v = pre[lane];     // halves: [0..31]=alpha2-pre, [32..63]=alpha1-pre
            float m = v;
            m = fmaxf(m, __shfl_xor(m, 16, 64)); m = fmaxf(m, __shfl_xor(m, 8, 64));
            m = fmaxf(m, __shfl_xor(m, 4, 64));  m = fmaxf(m, __shfl_xor(m, 2, 64));
            m = fmaxf(m, __shfl_xor(m, 1, 64));
            float e = expf(v - m);
            float ss = e;
            ss += __shfl_xor(ss, 16, 64); ss += __shfl_xor(ss, 8, 64);
            ss += __shfl_xor(ss, 4, 64);  ss += __shfl_xor(ss, 2, 64); ss += __shfl_xor(ss, 1, 64);
            float al = e / ss;
            if (lane < 32) { al2[lane] = al; if (b == 0) out[OA2 + (size_t)t * KK + lane] = al; }
            else           { al1[lane - 32] = al; if (b == 0) out[OA1 + (size_t)t * KK + (lane - 32)] = al; }
        } else if (w == 4 || w == 5) {
            int eg = 2 * b + (w - 4);
            const float4* wr = (const float4*)(Wu1 + (size_t)eg * D1);
            const float4* x4 = (const float4*)x1s;
            float4 a = wr[lane];
            float4 x = x4[(lane >> 2) * 5 + (lane & 3)];   // padded-chunk float4 index
            float s = DOT4(a, x);
            s = waveReduceSum(s);
            if (lane == 0) { uS[w - 4] = s; out[OU2 + (size_t)t * D2 + eg] = s; }
        } else if (w == 6) {
            float s = 0.f;
            if (lane < 32) {
                const float4* wr = (const float4*)(Wu0 + (size_t)b * D0);
                const float4* x4 = (const float4*)x0s;
                float4 a = wr[lane], x = x4[lane];
                s = DOT4(a, x);
            }
            s = waveReduceSum(s);
            if (lane == 0) { uS[2] = s; out[OU1 + (size_t)t * D1 + b] = s; }
        } else if (w == 7 && b < D0) {
            float s = 0.f;
            if (lane < 32) {
                const float4* mr = (const float4*)(ws + OFF_M0 + (size_t)b * D0);
                const float4* x4 = (const float4*)x0s;
                float4 a = mr[lane], x = x4[lane];
                s = DOT4(a, x);
            }
            s = waveReduceSum(s);
            if (lane == 0) {
                float xo = x0s[b];
                float xn = xo + ((1.f - g0) * s - g0 * xo) * DTTAU;
                __hip_atomic_store(&X0S[(p ^ 1) * D0 + b], xn, __ATOMIC_RELAXED, __HIP_MEMORY_SCOPE_AGENT);
                out[OX0 + (size_t)t * D0 + b] = xn;
            }
        }
        __syncthreads();

        // ---- P4: A-row dots from registers ----
        {
            const float4* x24 = (const float4*)x2s;
            float sa = 0.f, sb = 0.f;
            #pragma unroll
            for (int jj = 0; jj < 8; ++jj) {
                float4 x = x24[c * 9 + jj];
                sa += DOT4(a2r0[jj], x);
                sb += DOT4(a2r1[jj], x);
            }
            sa += __shfl_xor(sa, 1, 64); sa += __shfl_xor(sa, 2, 64);
            sa += __shfl_xor(sa, 4, 64); sa += __shfl_xor(sa, 8, 64);
            sb += __shfl_xor(sb, 1, 64); sb += __shfl_xor(sb, 2, 64);
            sb += __shfl_xor(sb, 4, 64); sb += __shfl_xor(sb, 8, 64);
            const float4* x14 = (const float4*)x1s;
            float sc = 0.f;
            #pragma unroll
            for (int jj = 0; jj < 4; ++jj) {
                float4 x = x14[c * 5 + jj];
                sc += DOT4(a1r[jj], x);
            }
            sc += __shfl_xor(sc, 1, 64); sc += __shfl_xor(sc, 2, 64);
            sc += __shfl_xor(sc, 4, 64); sc += __shfl_xor(sc, 8, 64);
            if (c == 0) { red2a[k] = sa; red2b[k] = sb; red1[k] = sc; }
        }
        __syncthreads();

        // ---- P5: combine over k, state update, publish ----
        if (w == 0) {
            float v = (lane < 32) ? al2[lane] * red2a[lane] : al2[lane - 32] * red2b[lane - 32];
            v += __shfl_xor(v, 16, 64); v += __shfl_xor(v, 8, 64); v += __shfl_xor(v, 4, 64);
            v += __shfl_xor(v, 2, 64);  v += __shfl_xor(v, 1, 64);
            if ((lane & 31) == 0) {
                int e = lane >> 5;
                int eg = 2 * b + e;
                float xo = x2s[(eg >> 5) * 36 + (eg & 31)];
                float xn = xo + ((1.f - g2) * v - g2 * xo + uS[e]) * DTTAU;
                __hip_atomic_store(&X2S[(p ^ 1) * D2 + eg], xn, __ATOMIC_RELAXED, __HIP_MEMORY_SCOPE_AGENT);
                out[OX2 + (size_t)t * D2 + eg] = xn;
                ws[OFF_S2T + (size_t)t * D2 + eg] = xn;
            }
        } else if (w == 1) {
            float v = (lane < 32) ? al1[lane] * red1[lane] : 0.f;
            v += __shfl_xor(v, 16, 64); v += __shfl_xor(v, 8, 64); v += __shfl_xor(v, 4, 64);
            v += __shfl_xor(v, 2, 64);  v += __shfl_xor(v, 1, 64);
            if (lane == 0) {
                float xo = x1s[(b >> 4) * 20 + (b & 15)];
                float xn = xo + ((1.f - g1) * v - g1 * xo + uS[2]) * DTTAU;
                __hip_atomic_store(&X1S[(p ^ 1) * D1 + b], xn, __ATOMIC_RELAXED, __HIP_MEMORY_SCOPE_AGENT);
                out[OX1 + (size_t)t * D1 + b] = xn;
            }
        }

        // ---- grid barrier (monotone counter; skip after last step) ----
        if (t < T_STEPS - 1) {
            __syncthreads();   // drains each wave's vmem stores before arrival
            if (tid == 0) {
                __hip_atomic_fetch_add(ctr, 1, __ATOMIC_RELEASE, __HIP_MEMORY_SCOPE_AGENT);
                const int target = NB * (t + 1);
                while (__hip_atomic_load(ctr, __ATOMIC_ACQUIRE, __HIP_MEMORY_SCOPE_AGENT) < target)
                    __builtin_amdgcn_s_sleep(4);
            }
            __syncthreads();
        }
    }
}

// ---------------- pen_actions for all t in parallel ----------------
__global__ __launch_bounds__(192) void pa_kernel(
    const float* __restrict__ Wp, const float* __restrict__ bp, float* __restrict__ ws)
{
    int t = blockIdx.x;
    int w = threadIdx.x >> 6, lane = threadIdx.x & 63;
    const float4* x2 = (const float4*)(ws + OFF_S2T + (size_t)t * D2);
    const float4* wr = (const float4*)(Wp + (size_t)w * D2);
    float p = 0.f;
    #pragma unroll
    for (int it = 0; it < 2; ++it) {
        float4 a = wr[lane + 64 * it], x = x2[lane + 64 * it];
        p += DOT4(a, x);
    }
    p = waveReduceSum(p);
    if (lane == 0) ws[OFF_PA + (size_t)t * 3 + w] = p + bp[w];
}

// ---------------- scalar pen recurrence (inherently serial, tiny) ----------------
__global__ void chain_kernel(float* __restrict__ ws, float* __restrict__ out)
{
    if (blockIdx.x != 0 || threadIdx.x != 0) return;
    float py = ws[OFF_PENS], px = ws[OFF_PENS + 1];
    for (int t = 0; t < T_STEPS; ++t) {
        float dy = ws[OFF_PA + t * 3], dx = ws[OFF_PA + t * 3 + 1], z = ws[OFF_PA + t * 3 + 2];
        float pdlp = fminf(z, 0.f) - log1pf(expf(-fabsf(z)));
        ws[OFF_PXYP + t * 3] = py; ws[OFF_PXYP + t * 3 + 1] = px; ws[OFF_PXYP + t * 3 + 2] = pdlp;
        float ny = py + dy, nx = px + dx;
        ny = 105.f / (1.f + expf(-(ny - 52.5f) * (4.f / 105.f)));
        nx = 105.f / (1.f + expf(-(nx - 52.5f) * (4.f / 105.f)));
        py = ny; px = nx;
        out[OPEN + (size_t)t * 2] = py;
        out[OPEN + (size_t)t * 2 + 1] = px;
        out[OPDLP + t] = pdlp;
    }
}

// ---------------- p_xy image ----------------
__global__ __launch_bounds__(256) void pxy_kernel(
    const float* __restrict__ plv, const float* __restrict__ ws, float* __restrict__ out)
{
    int t = blockIdx.x;
    const float* pxyp = ws + OFF_PXYP + (size_t)t * 3;
    float py = pxyp[0], px = pxyp[1], pdlp = pxyp[2];
    float inv_var = 1.0f / (expf(plv[0]) + 1e-16f);
    for (int p = threadIdx.x; p < NPIX; p += 256) {
        int i = p / IMGW, j = p % IMGW;
        float ddy = py - ((float)i + 0.5f);
        float ddx = px - ((float)j + 0.5f);
        float v = expf(-0.5f * inv_var * (ddy * ddy + ddx * ddx) + pdlp);
        out[OPXY + (size_t)t * NPIX + p] = v + 1e-16f;
    }
}

extern "C" void kernel_launch(void* const* d_in, const int* in_sizes, int n_in,
                              void* d_out, int out_size, void* d_ws, size_t ws_size,
                              hipStream_t stream)
{
    const void*  data = d_in[0];
    const float* z1  = (const float*)d_in[1];
    const float* z2  = (const float*)d_in[2];
    const float* gam = (const float*)d_in[3];
    const float* plv = (const float*)d_in[4];
    const float* Wa0 = (const float*)d_in[5];
    const float* Wa1 = (const float*)d_in[6];
    const float* ba0 = (const float*)d_in[7];
    const float* ba1 = (const float*)d_in[8];
    const float* Wu0 = (const float*)d_in[9];
    const float* Wu1 = (const float*)d_in[10];
    const float* Wp  = (const float*)d_in[11];
    const float* bp  = (const float*)d_in[12];
    const float* A0  = (const float*)d_in[13];
    const float* A1  = (const float*)d_in[14];
    const float* A2  = (const float*)d_in[15];
    float* out = (float*)d_out;
    float* ws  = (float*)d_ws;

    hipLaunchKernelGGL(setup_kernel, dim3(1), dim3(256), 0, stream, data, z2, ws);
    hipLaunchKernelGGL(m0_kernel, dim3(64), dim3(256), 0, stream, z1, A0, ws);
    hipLaunchKernelGGL(fill_kernel, dim3(128), dim3(256), 0, stream, z1, out);
    hipLaunchKernelGGL(persist_kernel, dim3(NB), dim3(NT), 0, stream,
                       A1, A2, Wu0, Wu1, Wa0, Wa1, ba0, ba1, gam, ws, out);
    hipLaunchKernelGGL(pa_kernel, dim3(T_STEPS), dim3(192), 0, stream, Wp, bp, ws);
    hipLaunchKernelGGL(chain_kernel, dim3(1), dim3(64), 0, stream, ws, out);
    hipLaunchKernelGGL(pxy_kernel, dim3(T_STEPS), dim3(256), 0, stream, plv, ws, out);
}

// Round 5
// 5926.251 us; speedup vs baseline: 1.9883x; 1.9883x over previous
//
#include <hip/hip_runtime.h>
#include <math.h>

#define T_STEPS 1000
#define KK 32
#define D0 128
#define D1 256
#define D2 512
#define IMGH 105
#define IMGW 105
#define NPIX (IMGH*IMGW)
#define DTTAU 0.01f

#define NB 256
#define NT 512

// ---- workspace float offsets ----
#define OFF_M0   0            // 128*128
#define OFF_X0S  16384        // 2*128  ping-pong x0
#define OFF_X1S  16640        // 2*256
#define OFF_X2S  17152        // 2*512
#define OFF_S2T  18176        // 1000*512  (x2 AFTER step t)
#define OFF_PA   530176       // 1000*3
#define OFF_PXYP 533176       // 1000*3
#define OFF_PENS 536176       // 2
#define OFF_CTR  536192       // 8 ints, 64B-strided (128 ints total)

// ---- output float offsets (reference return order, each stacked over T) ----
#define OA0  0
#define OA1  32000
#define OA2  64000
#define OU0  96000
#define OU1  224000
#define OU2  480000
#define OX0  992000
#define OX1  1120000
#define OX2  1376000
#define OPEN 1888000
#define OPXY 1890000
#define OPDLP 12915000

#define DOT4(a,b) ((a).x*(b).x + (a).y*(b).y + (a).z*(b).z + (a).w*(b).w)

__device__ __forceinline__ float waveReduceSum(float v) {
    for (int m = 32; m >= 1; m >>= 1) v += __shfl_xor(v, m, 64);
    return v;
}

// ---------------- setup: init exchange slots, pen0, barrier counters ----------------
__global__ __launch_bounds__(256) void setup_kernel(
    const void* __restrict__ dataRaw, const float* __restrict__ z2,
    float* __restrict__ ws)
{
    if (blockIdx.x != 0) return;
    int tid = threadIdx.x;

    if (tid < D0) (ws + OFF_X0S)[tid] = z2[tid];           // parity-0 slots = x(0)
    if (tid < D1) (ws + OFF_X1S)[tid] = 0.f;
    for (int i = tid; i < D2; i += 256) (ws + OFF_X2S)[i] = 0.f;
    if (tid < 128) ((int*)(ws + OFF_CTR))[tid] = 0;

    // pen0 = argwhere(data)[0]; robust to bool stored as uint8 or int32
    __shared__ int sMin;
    if (tid == 0) sMin = 0x7fffffff;
    __syncthreads();
    const unsigned char* db = (const unsigned char*)dataRaw;
    for (int i = tid; i < NPIX; i += 256) if (db[i]) atomicMin(&sMin, i);
    __syncthreads();
    if (sMin == 0x7fffffff) {
        const int* di = (const int*)dataRaw;
        for (int i = tid; i < NPIX; i += 256) if (di[i] != 0) atomicMin(&sMin, i);
    }
    __syncthreads();
    if (tid == 0) {
        int idx = (sMin == 0x7fffffff) ? 0 : sMin;
        (ws + OFF_PENS)[0] = (float)(idx / IMGW);
        (ws + OFF_PENS)[1] = (float)(idx % IMGW);
    }
}

// ---------------- M0 = sum_k z1[k] * A0[k] ----------------
__global__ __launch_bounds__(256) void m0_kernel(
    const float* __restrict__ z1, const float* __restrict__ A0, float* __restrict__ ws)
{
    int idx = blockIdx.x * 256 + threadIdx.x;
    if (idx < D0 * D0) {
        float s = 0.f;
        for (int k = 0; k < KK; k++) s += z1[k] * A0[(size_t)k * D0 * D0 + idx];
        ws[OFF_M0 + idx] = s;
    }
}

// ---------------- trivial outputs: alpha0 broadcast, u0 zeros ----------------
__global__ __launch_bounds__(256) void fill_kernel(const float* __restrict__ z1, float* __restrict__ out)
{
    size_t gid = (size_t)blockIdx.x * blockDim.x + threadIdx.x;
    size_t nthr = (size_t)gridDim.x * blockDim.x;
    for (size_t i = gid; i < 32000; i += nthr) out[OA0 + i] = z1[i & 31];
    for (size_t i = gid; i < 128000; i += nthr) out[OU0 + i] = 0.f;
}

// ---------------- persistent recurrence: A in registers, relaxed-atomic barrier ----------------
// block b owns: L2 elems {2b,2b+1} (all 32 k), L1 elem {b}, L0 row {b} (b<128).
// thread roles: k = tid>>4 (0..31), c = tid&15 (slice of the row).
__global__ __launch_bounds__(NT, 2) void persist_kernel(
    const float* __restrict__ A1, const float* __restrict__ A2,
    const float* __restrict__ Wu0, const float* __restrict__ Wu1,
    const float* __restrict__ Wa0, const float* __restrict__ Wa1,
    const float* __restrict__ ba0, const float* __restrict__ ba1,
    const float* __restrict__ gam,
    float* __restrict__ ws, float* __restrict__ out)
{
    const int b = blockIdx.x;
    const int tid = threadIdx.x;
    const int lane = tid & 63;
    const int w = tid >> 6;
    const int k = tid >> 4;
    const int c = tid & 15;

    // ---- load A into registers (once; statically indexed) ----
    float4 a2r0[8], a2r1[8], a1r[4];
    {
        const float4* p0 = (const float4*)(A2 + ((size_t)k * D2 + 2 * b) * D2 + c * 32);
        const float4* p1 = (const float4*)(A2 + ((size_t)k * D2 + 2 * b + 1) * D2 + c * 32);
        #pragma unroll
        for (int jj = 0; jj < 8; ++jj) { a2r0[jj] = p0[jj]; a2r1[jj] = p1[jj]; }
        const float4* p2 = (const float4*)(A1 + ((size_t)k * D1 + b) * D1 + c * 16);
        #pragma unroll
        for (int jj = 0; jj < 4; ++jj) a1r[jj] = p2[jj];
    }
    const float g0 = gam[0], g1 = gam[1], g2 = gam[2];

    __shared__ __align__(16) float x0s[D0];
    __shared__ __align__(16) float x1s[16 * 20];   // chunk c: 16 floats at c*20
    __shared__ __align__(16) float x2s[16 * 36];   // chunk c: 32 floats at c*36
    __shared__ float pre[64];
    __shared__ float red2a[KK], red2b[KK], red1[KK];
    __shared__ float uS[3];

    float* X0S = ws + OFF_X0S;
    float* X1S = ws + OFF_X1S;
    float* X2S = ws + OFF_X2S;
    int* ctr = (int*)(ws + OFF_CTR);

    #pragma unroll 1
    for (int t = 0; t < T_STEPS; ++t) {
        const int p = t & 1;

        // ---- P1: fetch x(t) (relaxed agent-scope: LLC-coherent, no cache maintenance) ----
        if (tid < D0)
            x0s[tid] = __hip_atomic_load(&X0S[p * D0 + tid], __ATOMIC_RELAXED, __HIP_MEMORY_SCOPE_AGENT);
        if (tid < D1)
            x1s[(tid >> 4) * 20 + (tid & 15)] =
                __hip_atomic_load(&X1S[p * D1 + tid], __ATOMIC_RELAXED, __HIP_MEMORY_SCOPE_AGENT);
        x2s[(tid >> 5) * 36 + (tid & 31)] =
            __hip_atomic_load(&X2S[p * D2 + tid], __ATOMIC_RELAXED, __HIP_MEMORY_SCOPE_AGENT);
        __syncthreads();

        // ---- P2: alpha-pre + A-dots (all threads) || u2/u1/M0+x0-publish (waves 4..7) ----
        {
            float s = 0.f;
            const float4* wr = (const float4*)(Wa1 + (size_t)k * D1 + c * 16);
            const float4* xc = (const float4*)(x1s + c * 20);
            #pragma unroll
            for (int jj = 0; jj < 4; ++jj) { float4 a = wr[jj], x = xc[jj]; s += DOT4(a, x); }
            s += __shfl_xor(s, 1, 64); s += __shfl_xor(s, 2, 64);
            s += __shfl_xor(s, 4, 64); s += __shfl_xor(s, 8, 64);
            if (c == 0) pre[k] = s + ba1[k];

            float s1 = 0.f;
            const float4* wr1 = (const float4*)(Wa0 + (size_t)k * D0 + c * 8);
            const float4* xc1 = (const float4*)(x0s + c * 8);
            #pragma unroll
            for (int jj = 0; jj < 2; ++jj) { float4 a = wr1[jj], x = xc1[jj]; s1 += DOT4(a, x); }
            s1 += __shfl_xor(s1, 1, 64); s1 += __shfl_xor(s1, 2, 64);
            s1 += __shfl_xor(s1, 4, 64); s1 += __shfl_xor(s1, 8, 64);
            if (c == 0) pre[32 + k] = s1 + ba0[k];

            const float4* x24 = (const float4*)x2s;
            float sa = 0.f, sb = 0.f;
            #pragma unroll
            for (int jj = 0; jj < 8; ++jj) {
                float4 x = x24[c * 9 + jj];
                sa += DOT4(a2r0[jj], x);
                sb += DOT4(a2r1[jj], x);
            }
            sa += __shfl_xor(sa, 1, 64); sa += __shfl_xor(sa, 2, 64);
            sa += __shfl_xor(sa, 4, 64); sa += __shfl_xor(sa, 8, 64);
            sb += __shfl_xor(sb, 1, 64); sb += __shfl_xor(sb, 2, 64);
            sb += __shfl_xor(sb, 4, 64); sb += __shfl_xor(sb, 8, 64);
            const float4* x14 = (const float4*)x1s;
            float sc = 0.f;
            #pragma unroll
            for (int jj = 0; jj < 4; ++jj) {
                float4 x = x14[c * 5 + jj];
                sc += DOT4(a1r[jj], x);
            }
            sc += __shfl_xor(sc, 1, 64); sc += __shfl_xor(sc, 2, 64);
            sc += __shfl_xor(sc, 4, 64); sc += __shfl_xor(sc, 8, 64);
            if (c == 0) { red2a[k] = sa; red2b[k] = sb; red1[k] = sc; }
        }
        if (w == 4 || w == 5) {
            int eg = 2 * b + (w - 4);
            const float4* wr = (const float4*)(Wu1 + (size_t)eg * D1);
            const float4* x4 = (const float4*)x1s;
            float4 a = wr[lane];
            float4 x = x4[(lane >> 2) * 5 + (lane & 3)];
            float s = DOT4(a, x);
            s = waveReduceSum(s);
            if (lane == 0) { uS[w - 4] = s; out[OU2 + (size_t)t * D2 + eg] = s; }
        } else if (w == 6) {
            float s = 0.f;
            if (lane < 32) {
                const float4* wr = (const float4*)(Wu0 + (size_t)b * D0);
                const float4* x4 = (const float4*)x0s;
                float4 a = wr[lane], x = x4[lane];
                s = DOT4(a, x);
            }
            s = waveReduceSum(s);
            if (lane == 0) { uS[2] = s; out[OU1 + (size_t)t * D1 + b] = s; }
        } else if (w == 7 && b < D0) {
            float s = 0.f;
            if (lane < 32) {
                const float4* mr = (const float4*)(ws + OFF_M0 + (size_t)b * D0);
                const float4* x4 = (const float4*)x0s;
                float4 a = mr[lane], x = x4[lane];
                s = DOT4(a, x);
            }
            s = waveReduceSum(s);
            if (lane == 0) {
                float xo = x0s[b];
                float xn = xo + ((1.f - g0) * s - g0 * xo) * DTTAU;
                __hip_atomic_store(&X0S[(p ^ 1) * D0 + b], xn, __ATOMIC_RELAXED, __HIP_MEMORY_SCOPE_AGENT);
                out[OX0 + (size_t)t * D0 + b] = xn;
            }
        }
        __syncthreads();

        // ---- P3 (wave0 only): softmax + combine in-register, publish x2/x1, barrier ----
        if (w == 0) {
            float pv = pre[lane];          // lanes 0-31: alpha2-pre; 32-63: alpha1-pre
            float m = pv;
            m = fmaxf(m, __shfl_xor(m, 16, 64)); m = fmaxf(m, __shfl_xor(m, 8, 64));
            m = fmaxf(m, __shfl_xor(m, 4, 64));  m = fmaxf(m, __shfl_xor(m, 2, 64));
            m = fmaxf(m, __shfl_xor(m, 1, 64));
            float e = expf(pv - m);
            float ss = e;
            ss += __shfl_xor(ss, 16, 64); ss += __shfl_xor(ss, 8, 64);
            ss += __shfl_xor(ss, 4, 64);  ss += __shfl_xor(ss, 2, 64); ss += __shfl_xor(ss, 1, 64);
            float al = e / ss;             // half-wave softmax
            if (b == 0) {
                if (lane < 32) out[OA2 + (size_t)t * KK + lane] = al;
                else           out[OA1 + (size_t)t * KK + (lane - 32)] = al;
            }
            float r1 = (lane < 32) ? red2a[lane] : red1[lane - 32];
            float r2 = (lane < 32) ? red2b[lane] : 0.f;
            float v1 = al * r1, v2 = al * r2;
            v1 += __shfl_xor(v1, 16, 64); v1 += __shfl_xor(v1, 8, 64);
            v1 += __shfl_xor(v1, 4, 64);  v1 += __shfl_xor(v1, 2, 64); v1 += __shfl_xor(v1, 1, 64);
            v2 += __shfl_xor(v2, 16, 64); v2 += __shfl_xor(v2, 8, 64);
            v2 += __shfl_xor(v2, 4, 64);  v2 += __shfl_xor(v2, 2, 64); v2 += __shfl_xor(v2, 1, 64);
            if (lane == 0) {
                int eg = 2 * b;
                float xo0 = x2s[(eg >> 5) * 36 + (eg & 31)];
                float xn0 = xo0 + ((1.f - g2) * v1 - g2 * xo0 + uS[0]) * DTTAU;
                __hip_atomic_store(&X2S[(p ^ 1) * D2 + eg], xn0, __ATOMIC_RELAXED, __HIP_MEMORY_SCOPE_AGENT);
                out[OX2 + (size_t)t * D2 + eg] = xn0;
                ws[OFF_S2T + (size_t)t * D2 + eg] = xn0;
                int eh = eg + 1;
                float xo1 = x2s[(eh >> 5) * 36 + (eh & 31)];
                float xn1 = xo1 + ((1.f - g2) * v2 - g2 * xo1 + uS[1]) * DTTAU;
                __hip_atomic_store(&X2S[(p ^ 1) * D2 + eh], xn1, __ATOMIC_RELAXED, __HIP_MEMORY_SCOPE_AGENT);
                out[OX2 + (size_t)t * D2 + eh] = xn1;
                ws[OFF_S2T + (size_t)t * D2 + eh] = xn1;
            }
            if (lane == 32) {
                float xo = x1s[(b >> 4) * 20 + (b & 15)];
                float xn = xo + ((1.f - g1) * v1 - g1 * xo + uS[2]) * DTTAU;
                __hip_atomic_store(&X1S[(p ^ 1) * D1 + b], xn, __ATOMIC_RELAXED, __HIP_MEMORY_SCOPE_AGENT);
                out[OX1 + (size_t)t * D1 + b] = xn;
            }
            if (t < T_STEPS - 1) {
                // drain this wave's sc1 stores (they ack at the coherency point), then arrive
                asm volatile("s_waitcnt vmcnt(0)" ::: "memory");
                if (lane == 0)
                    __hip_atomic_fetch_add(&ctr[(b & 7) * 16], 1, __ATOMIC_RELAXED, __HIP_MEMORY_SCOPE_AGENT);
                const int target = NB * (t + 1);
                if (lane < 8) {
                    int s;
                    do {
                        int v = __hip_atomic_load(&ctr[lane * 16], __ATOMIC_RELAXED, __HIP_MEMORY_SCOPE_AGENT);
                        s = v;
                        s += __shfl_xor(s, 1, 64);
                        s += __shfl_xor(s, 2, 64);
                        s += __shfl_xor(s, 4, 64);
                        if (s < target) __builtin_amdgcn_s_sleep(1);
                    } while (s < target);
                }
            }
        }
        __syncthreads();   // waves 1-7 park here; wave0 joins after spin -> release
    }
}

// ---------------- pen_actions for all t in parallel ----------------
__global__ __launch_bounds__(192) void pa_kernel(
    const float* __restrict__ Wp, const float* __restrict__ bp, float* __restrict__ ws)
{
    int t = blockIdx.x;
    int w = threadIdx.x >> 6, lane = threadIdx.x & 63;
    const float4* x2 = (const float4*)(ws + OFF_S2T + (size_t)t * D2);
    const float4* wr = (const float4*)(Wp + (size_t)w * D2);
    float p = 0.f;
    #pragma unroll
    for (int it = 0; it < 2; ++it) {
        float4 a = wr[lane + 64 * it], x = x2[lane + 64 * it];
        p += DOT4(a, x);
    }
    p = waveReduceSum(p);
    if (lane == 0) ws[OFF_PA + (size_t)t * 3 + w] = p + bp[w];
}

// ---------------- scalar pen recurrence (inherently serial, tiny) ----------------
__global__ void chain_kernel(float* __restrict__ ws, float* __restrict__ out)
{
    if (blockIdx.x != 0 || threadIdx.x != 0) return;
    float py = ws[OFF_PENS], px = ws[OFF_PENS + 1];
    for (int t = 0; t < T_STEPS; ++t) {
        float dy = ws[OFF_PA + t * 3], dx = ws[OFF_PA + t * 3 + 1], z = ws[OFF_PA + t * 3 + 2];
        float pdlp = fminf(z, 0.f) - log1pf(expf(-fabsf(z)));
        ws[OFF_PXYP + t * 3] = py; ws[OFF_PXYP + t * 3 + 1] = px; ws[OFF_PXYP + t * 3 + 2] = pdlp;
        float ny = py + dy, nx = px + dx;
        ny = 105.f / (1.f + expf(-(ny - 52.5f) * (4.f / 105.f)));
        nx = 105.f / (1.f + expf(-(nx - 52.5f) * (4.f / 105.f)));
        py = ny; px = nx;
        out[OPEN + (size_t)t * 2] = py;
        out[OPEN + (size_t)t * 2 + 1] = px;
        out[OPDLP + t] = pdlp;
    }
}

// ---------------- p_xy image ----------------
__global__ __launch_bounds__(256) void pxy_kernel(
    const float* __restrict__ plv, const float* __restrict__ ws, float* __restrict__ out)
{
    int t = blockIdx.x;
    const float* pxyp = ws + OFF_PXYP + (size_t)t * 3;
    float py = pxyp[0], px = pxyp[1], pdlp = pxyp[2];
    float inv_var = 1.0f / (expf(plv[0]) + 1e-16f);
    for (int p = threadIdx.x; p < NPIX; p += 256) {
        int i = p / IMGW, j = p % IMGW;
        float ddy = py - ((float)i + 0.5f);
        float ddx = px - ((float)j + 0.5f);
        float v = expf(-0.5f * inv_var * (ddy * ddy + ddx * ddx) + pdlp);
        out[OPXY + (size_t)t * NPIX + p] = v + 1e-16f;
    }
}

extern "C" void kernel_launch(void* const* d_in, const int* in_sizes, int n_in,
                              void* d_out, int out_size, void* d_ws, size_t ws_size,
                              hipStream_t stream)
{
    const void*  data = d_in[0];
    const float* z1  = (const float*)d_in[1];
    const float* z2  = (const float*)d_in[2];
    const float* gam = (const float*)d_in[3];
    const float* plv = (const float*)d_in[4];
    const float* Wa0 = (const float*)d_in[5];
    const float* Wa1 = (const float*)d_in[6];
    const float* ba0 = (const float*)d_in[7];
    const float* ba1 = (const float*)d_in[8];
    const float* Wu0 = (const float*)d_in[9];
    const float* Wu1 = (const float*)d_in[10];
    const float* Wp  = (const float*)d_in[11];
    const float* bp  = (const float*)d_in[12];
    const float* A0  = (const float*)d_in[13];
    const float* A1  = (const float*)d_in[14];
    const float* A2  = (const float*)d_in[15];
    float* out = (float*)d_out;
    float* ws  = (float*)d_ws;

    hipLaunchKernelGGL(setup_kernel, dim3(1), dim3(256), 0, stream, data, z2, ws);
    hipLaunchKernelGGL(m0_kernel, dim3(64), dim3(256), 0, stream, z1, A0, ws);
    hipLaunchKernelGGL(fill_kernel, dim3(128), dim3(256), 0, stream, z1, out);
    hipLaunchKernelGGL(persist_kernel, dim3(NB), dim3(NT), 0, stream,
                       A1, A2, Wu0, Wu1, Wa0, Wa1, ba0, ba1, gam, ws, out);
    hipLaunchKernelGGL(pa_kernel, dim3(T_STEPS), dim3(192), 0, stream, Wp, bp, ws);
    hipLaunchKernelGGL(chain_kernel, dim3(1), dim3(64), 0, stream, ws, out);
    hipLaunchKernelGGL(pxy_kernel, dim3(T_STEPS), dim3(256), 0, stream, plv, ws, out);
}